// Round 2
// baseline (826.967 us; speedup 1.0000x reference)
//
#include <hip/hip_runtime.h>
#include <hip/hip_bf16.h>

typedef unsigned short u16;
typedef unsigned int   u32;
typedef _Float16       f16;
typedef __attribute__((ext_vector_type(4))) float f32x4;
typedef __attribute__((ext_vector_type(8))) f16  f16x8;
typedef __attribute__((ext_vector_type(4))) f16  f16x4;

// ---------------------------------------------------------------------------
// fp32 -> fp16 vectorized conversion
// ---------------------------------------------------------------------------
__global__ __launch_bounds__(256) void conv_f32_f16(
    const float* __restrict__ in, f16* __restrict__ out, long long n4)
{
    long long i = (long long)blockIdx.x * 256 + threadIdx.x;
    if (i >= n4) return;
    f32x4 v = ((const f32x4*)in)[i];
    f16x4 o = { (f16)v[0], (f16)v[1], (f16)v[2], (f16)v[3] };
    ((f16x4*)out)[i] = o;
}

// ---------------------------------------------------------------------------
// transpose (+convert) -> fp16.  in: [rows][cols], out: [cols][rows]
// block (32,8), grid (cols/32, rows/32, batch)
// ---------------------------------------------------------------------------
template<typename TIN>
__global__ __launch_bounds__(256) void transpose_f16(
    const TIN* __restrict__ in, f16* __restrict__ out,
    int rows, int cols, long long sIn, long long sOut)
{
    __shared__ f16 tile[32][33];
    const int bz = blockIdx.z;
    const TIN* ib = in + sIn * bz;
    f16* ob = out + sOut * bz;
    const int c0 = blockIdx.x * 32, r0 = blockIdx.y * 32;
    const int tx = threadIdx.x, ty = threadIdx.y;
#pragma unroll
    for (int i = 0; i < 4; i++) {
        int r = ty + i * 8;
        TIN v = ib[(long long)(r0 + r) * cols + c0 + tx];
        tile[r][tx] = (f16)v;
    }
    __syncthreads();
#pragma unroll
    for (int i = 0; i < 4; i++) {
        int r = ty + i * 8;
        ob[(long long)(c0 + r) * rows + r0 + tx] = tile[tx][r];
    }
}

// ---------------------------------------------------------------------------
// b_comb[e] = sum_d bq[d] * W_bil[d][e]   (uses transposed fp16 W_bil)
// ---------------------------------------------------------------------------
__global__ __launch_bounds__(256) void bcomb_kernel(
    const float* __restrict__ bq, const f16* __restrict__ WbT, float* __restrict__ bc)
{
    const int e = blockIdx.x;
    const f16* row = WbT + (long long)e * 1024;
    const int t = threadIdx.x;
    float s = 0.f;
    for (int d = t; d < 1024; d += 256) s += bq[d] * (float)row[d];
#pragma unroll
    for (int off = 32; off; off >>= 1) s += __shfl_xor(s, off);
    __shared__ float red[4];
    if ((t & 63) == 0) red[t >> 6] = s;
    __syncthreads();
    if (t == 0) bc[e] = red[0] + red[1] + red[2] + red[3];
}

// ---------------------------------------------------------------------------
// GEMM  C[M,N] = A[M,K] @ B[N,K]^T (+ bias[N]).  fp16 inputs, f32 accum.
// 128x128 tile, BK=32, 256 threads (4 waves, 2x2 of 64x64 sub-tiles).
// grid (N/128, M/128, batch).
// ---------------------------------------------------------------------------
template<bool OUT_F16, bool HAS_BIAS>
__global__ __launch_bounds__(256) void gemm_bt(
    const f16* __restrict__ A, const f16* __restrict__ B,
    const float* __restrict__ bias, void* __restrict__ Cout,
    int M, int N, int K,
    long long sAb, long long sBb, long long sCb)
{
    __shared__ f16 Al[128][40];   // +16B pad: 80B row stride
    __shared__ f16 Bl[128][40];
    const int bz = blockIdx.z;
    const f16* Ab = A + sAb * bz + (long long)blockIdx.y * 128 * K;
    const f16* Bb = B + sBb * bz + (long long)blockIdx.x * 128 * K;
    const int t    = threadIdx.x;
    const int lane = t & 63;
    const int wid  = t >> 6;
    const int wr = wid >> 1, wc = wid & 1;
    const int srow = t >> 2;            // staging row 0..63 (+64)
    const int sch  = (t & 3) * 8;       // staging chunk (8 f16 = 16B)
    const int fr = lane & 15;
    const int kb = (lane >> 4) * 8;

    f32x4 acc[4][4];
#pragma unroll
    for (int m = 0; m < 4; m++)
#pragma unroll
        for (int n = 0; n < 4; n++) acc[m][n] = (f32x4){0.f, 0.f, 0.f, 0.f};

    for (int k0 = 0; k0 < K; k0 += 32) {
        // issue global loads before the barrier (prefetch overlap)
        f16x8 a0 = *(const f16x8*)(Ab + (long long)srow * K + k0 + sch);
        f16x8 a1 = *(const f16x8*)(Ab + (long long)(srow + 64) * K + k0 + sch);
        f16x8 b0 = *(const f16x8*)(Bb + (long long)srow * K + k0 + sch);
        f16x8 b1 = *(const f16x8*)(Bb + (long long)(srow + 64) * K + k0 + sch);
        __syncthreads();                 // previous iter done reading LDS
        *(f16x8*)&Al[srow][sch]      = a0;
        *(f16x8*)&Al[srow + 64][sch] = a1;
        *(f16x8*)&Bl[srow][sch]      = b0;
        *(f16x8*)&Bl[srow + 64][sch] = b1;
        __syncthreads();

        f16x8 af[4], bfr[4];
#pragma unroll
        for (int m = 0; m < 4; m++) af[m]  = *(const f16x8*)&Al[wr * 64 + m * 16 + fr][kb];
#pragma unroll
        for (int n = 0; n < 4; n++) bfr[n] = *(const f16x8*)&Bl[wc * 64 + n * 16 + fr][kb];
#pragma unroll
        for (int m = 0; m < 4; m++)
#pragma unroll
            for (int n = 0; n < 4; n++)
                acc[m][n] = __builtin_amdgcn_mfma_f32_16x16x32_f16(af[m], bfr[n], acc[m][n], 0, 0, 0);
    }

    const long long crow0 = (long long)blockIdx.y * 128 + wr * 64;
    const int ccol0 = blockIdx.x * 128 + wc * 64;
#pragma unroll
    for (int m = 0; m < 4; m++) {
#pragma unroll
        for (int n = 0; n < 4; n++) {
            const int col = ccol0 + n * 16 + fr;
            float bv = 0.f;
            if constexpr (HAS_BIAS) bv = bias[col];
#pragma unroll
            for (int i = 0; i < 4; i++) {
                const long long r = crow0 + m * 16 + (lane >> 4) * 4 + i;
                const float val = acc[m][n][i] + bv;
                if constexpr (OUT_F16)
                    ((f16*)Cout)[sCb * bz + r * N + col] = (f16)val;
                else
                    ((float*)Cout)[sCb * bz + r * N + col] = val;
            }
        }
    }
}

// ---------------------------------------------------------------------------
// Row softmax over 2048 cols, in-place fp32 + fp16 copy. 256 thr, 1 block/row.
// ---------------------------------------------------------------------------
__global__ __launch_bounds__(256) void softmax_rows(
    float* __restrict__ S, f16* __restrict__ P)
{
    const long long row = blockIdx.x;
    float* sr = S + row * 2048;
    f16*   pr = P + row * 2048;
    const int t = threadIdx.x;
    f32x4 v0 = ((f32x4*)sr)[t];
    f32x4 v1 = ((f32x4*)sr)[t + 256];
    float m = fmaxf(fmaxf(fmaxf(v0[0], v0[1]), fmaxf(v0[2], v0[3])),
                    fmaxf(fmaxf(v1[0], v1[1]), fmaxf(v1[2], v1[3])));
#pragma unroll
    for (int off = 32; off; off >>= 1) m = fmaxf(m, __shfl_xor(m, off));
    __shared__ float redm[4], reds[4];
    if ((t & 63) == 0) redm[t >> 6] = m;
    __syncthreads();
    m = fmaxf(fmaxf(redm[0], redm[1]), fmaxf(redm[2], redm[3]));
    float s = 0.f;
#pragma unroll
    for (int j = 0; j < 4; j++) { v0[j] = __expf(v0[j] - m); s += v0[j]; }
#pragma unroll
    for (int j = 0; j < 4; j++) { v1[j] = __expf(v1[j] - m); s += v1[j]; }
#pragma unroll
    for (int off = 32; off; off >>= 1) s += __shfl_xor(s, off);
    if ((t & 63) == 0) reds[t >> 6] = s;
    __syncthreads();
    s = reds[0] + reds[1] + reds[2] + reds[3];
    const float inv = 1.f / s;
#pragma unroll
    for (int j = 0; j < 4; j++) { v0[j] *= inv; v1[j] *= inv; }
    ((f32x4*)sr)[t]       = v0;
    ((f32x4*)sr)[t + 256] = v1;
    f16x4 p0 = { (f16)v0[0], (f16)v0[1], (f16)v0[2], (f16)v0[3] };
    f16x4 p1 = { (f16)v1[0], (f16)v1[1], (f16)v1[2], (f16)v1[3] };
    ((f16x4*)pr)[t]       = p0;
    ((f16x4*)pr)[t + 256] = p1;
}

// ---------------------------------------------------------------------------
extern "C" void kernel_launch(void* const* d_in, const int* in_sizes, int n_in,
                              void* d_out, int out_size, void* d_ws, size_t ws_size,
                              hipStream_t stream)
{
    const int B = 8, QL = 2048, KL = 2048, D = 1024;
    const long long BT = (long long)B * QL;           // 16384 tokens

    const float* k_in = (const float*)d_in[0];
    const float* q_in = (const float*)d_in[1];
    const float* Wk   = (const float*)d_in[2];
    const float* bk   = (const float*)d_in[3];
    const float* Wq   = (const float*)d_in[4];
    const float* bq   = (const float*)d_in[5];
    const float* Wb   = (const float*)d_in[6];
    const float* Wp   = (const float*)d_in[7];
    const float* bp   = (const float*)d_in[8];

    float* out   = (float*)d_out;                     // [8,2048,1024]
    float* score = out + BT * D;                      // [8,2048,2048]

    f16* w = (f16*)d_ws;
    f16* k_h   = w;  w += BT * D;
    f16* q_h   = w;  w += BT * D;
    f16* kx_h  = w;  w += BT * D;
    f16* kxT   = w;  w += (long long)B * D * KL;
    f16* qw_h  = w;  w += BT * D;
    f16* oa_h  = w;  w += BT * D;
    f16* P_h   = w;  w += (long long)B * QL * KL;
    f16* Wk_h  = w;  w += D * D;
    f16* WqT   = w;  w += D * D;
    f16* WbT   = w;  w += D * D;
    f16* Wp_h  = w;  w += D * D;
    f16* WcT   = w;  w += D * D;
    float* bc  = (float*)w;                           // 1024 f32

    dim3 b256(256);
    dim3 tb(32, 8);

    // fp32 -> fp16 conversions
    conv_f32_f16<<<(int)(BT * D / 4 / 256), b256, 0, stream>>>(k_in, k_h, BT * D / 4);
    conv_f32_f16<<<(int)(BT * D / 4 / 256), b256, 0, stream>>>(q_in, q_h, BT * D / 4);
    conv_f32_f16<<<D * D / 4 / 256, b256, 0, stream>>>(Wk, Wk_h, D * D / 4);
    conv_f32_f16<<<D * D / 4 / 256, b256, 0, stream>>>(Wp, Wp_h, D * D / 4);
    // transposed fp16 weights:  WqT[c][d] = Wq[d][c],  WbT[e][d] = W_bil[d][e]
    transpose_f16<float><<<dim3(32, 32, 1), tb, 0, stream>>>(Wq, WqT, D, D, 0, 0);
    transpose_f16<float><<<dim3(32, 32, 1), tb, 0, stream>>>(Wb, WbT, D, D, 0, 0);
    // folded bias: bc[e] = sum_d bq[d] * W_bil[d][e]
    bcomb_kernel<<<D, b256, 0, stream>>>(bq, WbT, bc);
    // folded weight: WcT[e][c] = sum_d W_bil[d][e] * Wq[d][c]  (= (Wq^T W_bil)^T)
    gemm_bt<true, false><<<dim3(8, 8, 1), b256, 0, stream>>>(
        WbT, WqT, nullptr, WcT, D, D, D, 0, 0, 0);
    // kx = k @ Wk^T + bk
    gemm_bt<true, true><<<dim3(8, 128, 1), b256, 0, stream>>>(
        k_h, Wk_h, bk, kx_h, (int)BT, D, D, 0, 0, 0);
    // qw = q @ Wc + bc
    gemm_bt<true, true><<<dim3(8, 128, 1), b256, 0, stream>>>(
        q_h, WcT, bc, qw_h, (int)BT, D, D, 0, 0, 0);
    // kxT[b][d][t] = kx[b][t][d]
    transpose_f16<f16><<<dim3(D / 32, KL / 32, B), tb, 0, stream>>>(
        kx_h, kxT, KL, D, (long long)KL * D, (long long)D * KL);
    // S = qw @ kx^T  (raw logits straight into d_out score region, fp32)
    gemm_bt<false, false><<<dim3(16, 16, 8), b256, 0, stream>>>(
        qw_h, kx_h, nullptr, score, QL, KL, D,
        (long long)QL * D, (long long)KL * D, (long long)QL * KL);
    // softmax in place + fp16 P for PV
    softmax_rows<<<B * QL, b256, 0, stream>>>(score, P_h);
    // out_attn = P @ kx   (via kxT, bt-form)
    gemm_bt<true, false><<<dim3(8, 16, 8), b256, 0, stream>>>(
        P_h, kxT, nullptr, oa_h, QL, D, KL,
        (long long)QL * KL, (long long)D * KL, (long long)QL * D);
    // out = out_attn @ Wp^T + bp
    gemm_bt<false, true><<<dim3(8, 128, 1), b256, 0, stream>>>(
        oa_h, Wp_h, bp, out, (int)BT, D, D, 0, 0, 0);
}

// Round 3
// 813.841 us; speedup vs baseline: 1.0161x; 1.0161x over previous
//
#include <hip/hip_runtime.h>
#include <hip/hip_bf16.h>

typedef unsigned short u16;
typedef unsigned int   u32;
typedef _Float16       f16;
typedef __attribute__((ext_vector_type(4))) float f32x4;
typedef __attribute__((ext_vector_type(8))) f16  f16x8;
typedef __attribute__((ext_vector_type(4))) f16  f16x4;

#define GLOAD_LDS16(gsrc, ldst)                                              \
    __builtin_amdgcn_global_load_lds(                                        \
        (const __attribute__((address_space(1))) void*)(gsrc),               \
        (__attribute__((address_space(3))) void*)(ldst), 16, 0, 0)

// ---------------------------------------------------------------------------
// fp32 -> fp16 vectorized conversion
// ---------------------------------------------------------------------------
__global__ __launch_bounds__(256) void conv_f32_f16(
    const float* __restrict__ in, f16* __restrict__ out, long long n4)
{
    long long i = (long long)blockIdx.x * 256 + threadIdx.x;
    if (i >= n4) return;
    f32x4 v = ((const f32x4*)in)[i];
    f16x4 o = { (f16)v[0], (f16)v[1], (f16)v[2], (f16)v[3] };
    ((f16x4*)out)[i] = o;
}

// ---------------------------------------------------------------------------
// transpose (+convert) -> fp16.  in: [rows][cols], out: [cols][rows]
// block (32,8), grid (cols/32, rows/32, batch)
// ---------------------------------------------------------------------------
template<typename TIN>
__global__ __launch_bounds__(256) void transpose_f16(
    const TIN* __restrict__ in, f16* __restrict__ out,
    int rows, int cols, long long sIn, long long sOut)
{
    __shared__ f16 tile[32][33];
    const int bz = blockIdx.z;
    const TIN* ib = in + sIn * bz;
    f16* ob = out + sOut * bz;
    const int c0 = blockIdx.x * 32, r0 = blockIdx.y * 32;
    const int tx = threadIdx.x, ty = threadIdx.y;
#pragma unroll
    for (int i = 0; i < 4; i++) {
        int r = ty + i * 8;
        TIN v = ib[(long long)(r0 + r) * cols + c0 + tx];
        tile[r][tx] = (f16)v;
    }
    __syncthreads();
#pragma unroll
    for (int i = 0; i < 4; i++) {
        int r = ty + i * 8;
        ob[(long long)(c0 + r) * rows + r0 + tx] = tile[tx][r];
    }
}

// ---------------------------------------------------------------------------
// b_comb[e] = sum_d bq[d] * W_bil[d][e]   (uses transposed fp16 W_bil)
// ---------------------------------------------------------------------------
__global__ __launch_bounds__(256) void bcomb_kernel(
    const float* __restrict__ bq, const f16* __restrict__ WbT, float* __restrict__ bc)
{
    const int e = blockIdx.x;
    const f16* row = WbT + (long long)e * 1024;
    const int t = threadIdx.x;
    float s = 0.f;
    for (int d = t; d < 1024; d += 256) s += bq[d] * (float)row[d];
#pragma unroll
    for (int off = 32; off; off >>= 1) s += __shfl_xor(s, off);
    __shared__ float red[4];
    if ((t & 63) == 0) red[t >> 6] = s;
    __syncthreads();
    if (t == 0) bc[e] = red[0] + red[1] + red[2] + red[3];
}

// ---------------------------------------------------------------------------
// GEMM  C[M,N] = A[M,K] @ B[N,K]^T (+ bias[N]).  fp16 inputs, f32 accum.
// m97 structure: 128x128 tile, BK=32, 256 threads (4 waves, 2x2 of 64x64
// sub-tiles), global_load_lds width-16 staging into LINEAR LDS (no pad).
// grid (N/128, M/128, batch).
// ---------------------------------------------------------------------------
template<bool OUT_F16, bool HAS_BIAS>
__global__ __launch_bounds__(256) void gemm_bt(
    const f16* __restrict__ A, const f16* __restrict__ B,
    const float* __restrict__ bias, void* __restrict__ Cout,
    int M, int N, int K,
    long long sAb, long long sBb, long long sCb)
{
    __shared__ f16 Al[128][32];   // linear: gload_lds dest must be contiguous
    __shared__ f16 Bl[128][32];
    const int bz = blockIdx.z;
    const f16* Ab = A + sAb * bz + (long long)blockIdx.y * 128 * K;
    const f16* Bb = B + sBb * bz + (long long)blockIdx.x * 128 * K;
    const int t    = threadIdx.x;
    const int lane = t & 63;
    const int wid  = t >> 6;
    const int wr = wid >> 1, wc = wid & 1;
    const int fr = lane & 15;
    const int kb = (lane >> 4) * 8;

    // staging: wave w owns rows [32w,32w+32) of both tiles, as 2 chunks of 16
    // rows; within a 1KB chunk lane l -> row base+ (l>>2), f16 col (l&3)*8.
    const int lrow = lane >> 2;
    const int lcol = (lane & 3) * 8;
    const int r0 = wid * 32;
    const f16* gA0 = Ab + (long long)(r0 + lrow) * K + lcol;
    const f16* gA1 = Ab + (long long)(r0 + 16 + lrow) * K + lcol;
    const f16* gB0 = Bb + (long long)(r0 + lrow) * K + lcol;
    const f16* gB1 = Bb + (long long)(r0 + 16 + lrow) * K + lcol;
    f16* lA0 = &Al[r0 + lrow][lcol];
    f16* lA1 = &Al[r0 + 16 + lrow][lcol];
    f16* lB0 = &Bl[r0 + lrow][lcol];
    f16* lB1 = &Bl[r0 + 16 + lrow][lcol];

    f32x4 acc[4][4];
#pragma unroll
    for (int m = 0; m < 4; m++)
#pragma unroll
        for (int n = 0; n < 4; n++) acc[m][n] = (f32x4){0.f, 0.f, 0.f, 0.f};

    for (int k0 = 0; k0 < K; k0 += 32) {
        __syncthreads();                 // all waves done reading prev tile
        GLOAD_LDS16(gA0 + k0, lA0);
        GLOAD_LDS16(gA1 + k0, lA1);
        GLOAD_LDS16(gB0 + k0, lB0);
        GLOAD_LDS16(gB1 + k0, lB1);
        __syncthreads();                 // vmcnt(0) drained here by compiler

        f16x8 af[4], bfr[4];
#pragma unroll
        for (int m = 0; m < 4; m++) af[m]  = *(const f16x8*)&Al[wr * 64 + m * 16 + fr][kb];
#pragma unroll
        for (int n = 0; n < 4; n++) bfr[n] = *(const f16x8*)&Bl[wc * 64 + n * 16 + fr][kb];
#pragma unroll
        for (int m = 0; m < 4; m++)
#pragma unroll
            for (int n = 0; n < 4; n++)
                acc[m][n] = __builtin_amdgcn_mfma_f32_16x16x32_f16(af[m], bfr[n], acc[m][n], 0, 0, 0);
    }

    const long long crow0 = (long long)blockIdx.y * 128 + wr * 64;
    const int ccol0 = blockIdx.x * 128 + wc * 64;
#pragma unroll
    for (int m = 0; m < 4; m++) {
#pragma unroll
        for (int n = 0; n < 4; n++) {
            const int col = ccol0 + n * 16 + fr;
            float bv = 0.f;
            if constexpr (HAS_BIAS) bv = bias[col];
#pragma unroll
            for (int i = 0; i < 4; i++) {
                const long long r = crow0 + m * 16 + (lane >> 4) * 4 + i;
                const float val = acc[m][n][i] + bv;
                if constexpr (OUT_F16)
                    ((f16*)Cout)[sCb * bz + r * N + col] = (f16)val;
                else
                    ((float*)Cout)[sCb * bz + r * N + col] = val;
            }
        }
    }
}

// ---------------------------------------------------------------------------
// Row softmax over 2048 cols, in-place fp32 + fp16 copy. 256 thr, 1 block/row.
// ---------------------------------------------------------------------------
__global__ __launch_bounds__(256) void softmax_rows(
    float* __restrict__ S, f16* __restrict__ P)
{
    const long long row = blockIdx.x;
    float* sr = S + row * 2048;
    f16*   pr = P + row * 2048;
    const int t = threadIdx.x;
    f32x4 v0 = ((f32x4*)sr)[t];
    f32x4 v1 = ((f32x4*)sr)[t + 256];
    float m = fmaxf(fmaxf(fmaxf(v0[0], v0[1]), fmaxf(v0[2], v0[3])),
                    fmaxf(fmaxf(v1[0], v1[1]), fmaxf(v1[2], v1[3])));
#pragma unroll
    for (int off = 32; off; off >>= 1) m = fmaxf(m, __shfl_xor(m, off));
    __shared__ float redm[4], reds[4];
    if ((t & 63) == 0) redm[t >> 6] = m;
    __syncthreads();
    m = fmaxf(fmaxf(redm[0], redm[1]), fmaxf(redm[2], redm[3]));
    float s = 0.f;
#pragma unroll
    for (int j = 0; j < 4; j++) { v0[j] = __expf(v0[j] - m); s += v0[j]; }
#pragma unroll
    for (int j = 0; j < 4; j++) { v1[j] = __expf(v1[j] - m); s += v1[j]; }
#pragma unroll
    for (int off = 32; off; off >>= 1) s += __shfl_xor(s, off);
    if ((t & 63) == 0) reds[t >> 6] = s;
    __syncthreads();
    s = reds[0] + reds[1] + reds[2] + reds[3];
    const float inv = 1.f / s;
#pragma unroll
    for (int j = 0; j < 4; j++) { v0[j] *= inv; v1[j] *= inv; }
    ((f32x4*)sr)[t]       = v0;
    ((f32x4*)sr)[t + 256] = v1;
    f16x4 p0 = { (f16)v0[0], (f16)v0[1], (f16)v0[2], (f16)v0[3] };
    f16x4 p1 = { (f16)v1[0], (f16)v1[1], (f16)v1[2], (f16)v1[3] };
    ((f16x4*)pr)[t]       = p0;
    ((f16x4*)pr)[t + 256] = p1;
}

// ---------------------------------------------------------------------------
extern "C" void kernel_launch(void* const* d_in, const int* in_sizes, int n_in,
                              void* d_out, int out_size, void* d_ws, size_t ws_size,
                              hipStream_t stream)
{
    const int B = 8, QL = 2048, KL = 2048, D = 1024;
    const long long BT = (long long)B * QL;           // 16384 tokens

    const float* k_in = (const float*)d_in[0];
    const float* q_in = (const float*)d_in[1];
    const float* Wk   = (const float*)d_in[2];
    const float* bk   = (const float*)d_in[3];
    const float* Wq   = (const float*)d_in[4];
    const float* bq   = (const float*)d_in[5];
    const float* Wb   = (const float*)d_in[6];
    const float* Wp   = (const float*)d_in[7];
    const float* bp   = (const float*)d_in[8];

    float* out   = (float*)d_out;                     // [8,2048,1024]
    float* score = out + BT * D;                      // [8,2048,2048]

    f16* w = (f16*)d_ws;
    f16* k_h   = w;  w += BT * D;
    f16* q_h   = w;  w += BT * D;
    f16* kx_h  = w;  w += BT * D;
    f16* kxT   = w;  w += (long long)B * D * KL;
    f16* qw_h  = w;  w += BT * D;
    f16* oa_h  = w;  w += BT * D;
    f16* P_h   = w;  w += (long long)B * QL * KL;
    f16* Wk_h  = w;  w += D * D;
    f16* WqT   = w;  w += D * D;
    f16* WbT   = w;  w += D * D;
    f16* Wp_h  = w;  w += D * D;
    f16* WcT   = w;  w += D * D;
    float* bc  = (float*)w;                           // 1024 f32

    dim3 b256(256);
    dim3 tb(32, 8);

    // fp32 -> fp16 conversions
    conv_f32_f16<<<(int)(BT * D / 4 / 256), b256, 0, stream>>>(k_in, k_h, BT * D / 4);
    conv_f32_f16<<<(int)(BT * D / 4 / 256), b256, 0, stream>>>(q_in, q_h, BT * D / 4);
    conv_f32_f16<<<D * D / 4 / 256, b256, 0, stream>>>(Wk, Wk_h, D * D / 4);
    conv_f32_f16<<<D * D / 4 / 256, b256, 0, stream>>>(Wp, Wp_h, D * D / 4);
    // transposed fp16 weights:  WqT[c][d] = Wq[d][c],  WbT[e][d] = W_bil[d][e]
    transpose_f16<float><<<dim3(32, 32, 1), tb, 0, stream>>>(Wq, WqT, D, D, 0, 0);
    transpose_f16<float><<<dim3(32, 32, 1), tb, 0, stream>>>(Wb, WbT, D, D, 0, 0);
    // folded bias: bc[e] = sum_d bq[d] * W_bil[d][e]
    bcomb_kernel<<<D, b256, 0, stream>>>(bq, WbT, bc);
    // folded weight: WcT[e][c] = sum_d W_bil[d][e] * Wq[d][c]  (= (Wq^T W_bil)^T)
    gemm_bt<true, false><<<dim3(8, 8, 1), b256, 0, stream>>>(
        WbT, WqT, nullptr, WcT, D, D, D, 0, 0, 0);
    // kx = k @ Wk^T + bk
    gemm_bt<true, true><<<dim3(8, 128, 1), b256, 0, stream>>>(
        k_h, Wk_h, bk, kx_h, (int)BT, D, D, 0, 0, 0);
    // qw = q @ Wc + bc
    gemm_bt<true, true><<<dim3(8, 128, 1), b256, 0, stream>>>(
        q_h, WcT, bc, qw_h, (int)BT, D, D, 0, 0, 0);
    // kxT[b][d][t] = kx[b][t][d]
    transpose_f16<f16><<<dim3(D / 32, KL / 32, B), tb, 0, stream>>>(
        kx_h, kxT, KL, D, (long long)KL * D, (long long)D * KL);
    // S = qw @ kx^T  (raw logits straight into d_out score region, fp32)
    gemm_bt<false, false><<<dim3(16, 16, 8), b256, 0, stream>>>(
        qw_h, kx_h, nullptr, score, QL, KL, D,
        (long long)QL * D, (long long)KL * D, (long long)QL * KL);
    // softmax in place + fp16 P for PV
    softmax_rows<<<B * QL, b256, 0, stream>>>(score, P_h);
    // out_attn = P @ kx   (via kxT, bt-form)
    gemm_bt<true, false><<<dim3(8, 16, 8), b256, 0, stream>>>(
        P_h, kxT, nullptr, oa_h, QL, D, KL,
        (long long)QL * KL, (long long)D * KL, (long long)QL * D);
    // out = out_attn @ Wp^T + bp
    gemm_bt<false, true><<<dim3(8, 128, 1), b256, 0, stream>>>(
        oa_h, Wp_h, bp, out, (int)BT, D, D, 0, 0, 0);
}

// Round 4
// 801.310 us; speedup vs baseline: 1.0320x; 1.0156x over previous
//
#include <hip/hip_runtime.h>
#include <hip/hip_bf16.h>

typedef unsigned short u16;
typedef unsigned int   u32;
typedef _Float16       f16;
typedef __attribute__((ext_vector_type(4))) float f32x4;
typedef __attribute__((ext_vector_type(8))) f16  f16x8;
typedef __attribute__((ext_vector_type(4))) f16  f16x4;

#define GLOAD_LDS16(gsrc, ldst)                                              \
    __builtin_amdgcn_global_load_lds(                                        \
        (const __attribute__((address_space(1))) void*)(gsrc),               \
        (__attribute__((address_space(3))) void*)(ldst), 16, 0, 0)

// ---------------------------------------------------------------------------
// fp32 -> fp16 vectorized conversion
// ---------------------------------------------------------------------------
__global__ __launch_bounds__(256) void conv_f32_f16(
    const float* __restrict__ in, f16* __restrict__ out, long long n4)
{
    long long i = (long long)blockIdx.x * 256 + threadIdx.x;
    if (i >= n4) return;
    f32x4 v = ((const f32x4*)in)[i];
    f16x4 o = { (f16)v[0], (f16)v[1], (f16)v[2], (f16)v[3] };
    ((f16x4*)out)[i] = o;
}

// ---------------------------------------------------------------------------
// transpose (+convert) -> fp16.  in: [rows][cols], out: [cols][rows]
// block (32,8), grid (cols/32, rows/32, batch)
// ---------------------------------------------------------------------------
template<typename TIN>
__global__ __launch_bounds__(256) void transpose_f16(
    const TIN* __restrict__ in, f16* __restrict__ out,
    int rows, int cols, long long sIn, long long sOut)
{
    __shared__ f16 tile[32][33];
    const int bz = blockIdx.z;
    const TIN* ib = in + sIn * bz;
    f16* ob = out + sOut * bz;
    const int c0 = blockIdx.x * 32, r0 = blockIdx.y * 32;
    const int tx = threadIdx.x, ty = threadIdx.y;
#pragma unroll
    for (int i = 0; i < 4; i++) {
        int r = ty + i * 8;
        TIN v = ib[(long long)(r0 + r) * cols + c0 + tx];
        tile[r][tx] = (f16)v;
    }
    __syncthreads();
#pragma unroll
    for (int i = 0; i < 4; i++) {
        int r = ty + i * 8;
        ob[(long long)(c0 + r) * rows + r0 + tx] = tile[tx][r];
    }
}

// ---------------------------------------------------------------------------
// b_comb[e] = sum_d bq[d] * W_bil[d][e]   (uses transposed fp16 W_bil)
// ---------------------------------------------------------------------------
__global__ __launch_bounds__(256) void bcomb_kernel(
    const float* __restrict__ bq, const f16* __restrict__ WbT, float* __restrict__ bc)
{
    const int e = blockIdx.x;
    const f16* row = WbT + (long long)e * 1024;
    const int t = threadIdx.x;
    float s = 0.f;
    for (int d = t; d < 1024; d += 256) s += bq[d] * (float)row[d];
#pragma unroll
    for (int off = 32; off; off >>= 1) s += __shfl_xor(s, off);
    __shared__ float red[4];
    if ((t & 63) == 0) red[t >> 6] = s;
    __syncthreads();
    if (t == 0) bc[e] = red[0] + red[1] + red[2] + red[3];
}

// ---------------------------------------------------------------------------
// GEMM  C[M,N] = A[M,K] @ B[N,K]^T (+ bias[N]).  fp16 inputs, f32 accum.
// 128x128 tile, BK=32, 256 threads (4 waves, 2x2 of 64x64 sub-tiles).
// 2-phase double-buffered LDS: stage(next) issued first, compute(cur), ONE
// __syncthreads per K-step (vmcnt(0) drain lands AFTER the MFMA cluster).
// grid (N/128, M/128, batch).
// ---------------------------------------------------------------------------
template<bool OUT_F16, bool HAS_BIAS>
__global__ __launch_bounds__(256) void gemm_bt(
    const f16* __restrict__ A, const f16* __restrict__ B,
    const float* __restrict__ bias, void* __restrict__ Cout,
    int M, int N, int K,
    long long sAb, long long sBb, long long sCb)
{
    __shared__ f16 Al[2][128][32];   // linear: gload_lds dest must be contiguous
    __shared__ f16 Bl[2][128][32];
    const int bz = blockIdx.z;
    const f16* Ab = A + sAb * bz + (long long)blockIdx.y * 128 * K;
    const f16* Bb = B + sBb * bz + (long long)blockIdx.x * 128 * K;
    const int t    = threadIdx.x;
    const int lane = t & 63;
    const int wid  = t >> 6;
    const int wr = wid >> 1, wc = wid & 1;
    const int fr = lane & 15;
    const int kb = (lane >> 4) * 8;

    // staging: wave w owns rows [32w,32w+32) of both tiles, as 2 chunks of 16
    // rows; within a 1KB chunk lane l -> row base + (l>>2), f16 col (l&3)*8.
    const int lrow = lane >> 2;
    const int lcol = (lane & 3) * 8;
    const int r0 = wid * 32;
    const f16* gA0 = Ab + (long long)(r0 + lrow) * K + lcol;
    const f16* gA1 = Ab + (long long)(r0 + 16 + lrow) * K + lcol;
    const f16* gB0 = Bb + (long long)(r0 + lrow) * K + lcol;
    const f16* gB1 = Bb + (long long)(r0 + 16 + lrow) * K + lcol;

    f32x4 acc[4][4];
#pragma unroll
    for (int m = 0; m < 4; m++)
#pragma unroll
        for (int n = 0; n < 4; n++) acc[m][n] = (f32x4){0.f, 0.f, 0.f, 0.f};

    // prologue: stage tile 0 into buffer 0
    GLOAD_LDS16(gA0, &Al[0][r0 + lrow][lcol]);
    GLOAD_LDS16(gA1, &Al[0][r0 + 16 + lrow][lcol]);
    GLOAD_LDS16(gB0, &Bl[0][r0 + lrow][lcol]);
    GLOAD_LDS16(gB1, &Bl[0][r0 + 16 + lrow][lcol]);
    __syncthreads();

    int cur = 0;
    for (int k0 = 0; k0 < K - 32; k0 += 32) {
        // issue next-tile staging into the other buffer (completes by the
        // barrier below -- latency hidden under ds_read + MFMA)
        const int nxt = cur ^ 1;
        GLOAD_LDS16(gA0 + k0 + 32, &Al[nxt][r0 + lrow][lcol]);
        GLOAD_LDS16(gA1 + k0 + 32, &Al[nxt][r0 + 16 + lrow][lcol]);
        GLOAD_LDS16(gB0 + k0 + 32, &Bl[nxt][r0 + lrow][lcol]);
        GLOAD_LDS16(gB1 + k0 + 32, &Bl[nxt][r0 + 16 + lrow][lcol]);

        f16x8 af[4], bfr[4];
#pragma unroll
        for (int m = 0; m < 4; m++) af[m]  = *(const f16x8*)&Al[cur][wr * 64 + m * 16 + fr][kb];
#pragma unroll
        for (int n = 0; n < 4; n++) bfr[n] = *(const f16x8*)&Bl[cur][wc * 64 + n * 16 + fr][kb];
#pragma unroll
        for (int m = 0; m < 4; m++)
#pragma unroll
            for (int n = 0; n < 4; n++)
                acc[m][n] = __builtin_amdgcn_mfma_f32_16x16x32_f16(af[m], bfr[n], acc[m][n], 0, 0, 0);

        __syncthreads();   // drains vmcnt(0) AFTER compute; next tile ready
        cur = nxt;
    }

    {   // final tile: no staging
        f16x8 af[4], bfr[4];
#pragma unroll
        for (int m = 0; m < 4; m++) af[m]  = *(const f16x8*)&Al[cur][wr * 64 + m * 16 + fr][kb];
#pragma unroll
        for (int n = 0; n < 4; n++) bfr[n] = *(const f16x8*)&Bl[cur][wc * 64 + n * 16 + fr][kb];
#pragma unroll
        for (int m = 0; m < 4; m++)
#pragma unroll
            for (int n = 0; n < 4; n++)
                acc[m][n] = __builtin_amdgcn_mfma_f32_16x16x32_f16(af[m], bfr[n], acc[m][n], 0, 0, 0);
    }

    const long long crow0 = (long long)blockIdx.y * 128 + wr * 64;
    const int ccol0 = blockIdx.x * 128 + wc * 64;
#pragma unroll
    for (int m = 0; m < 4; m++) {
#pragma unroll
        for (int n = 0; n < 4; n++) {
            const int col = ccol0 + n * 16 + fr;
            float bv = 0.f;
            if constexpr (HAS_BIAS) bv = bias[col];
#pragma unroll
            for (int i = 0; i < 4; i++) {
                const long long r = crow0 + m * 16 + (lane >> 4) * 4 + i;
                const float val = acc[m][n][i] + bv;
                if constexpr (OUT_F16)
                    ((f16*)Cout)[sCb * bz + r * N + col] = (f16)val;
                else
                    ((float*)Cout)[sCb * bz + r * N + col] = val;
            }
        }
    }
}

// ---------------------------------------------------------------------------
// Row softmax over 2048 cols, in-place fp32 + fp16 copy. 256 thr, 1 block/row.
// ---------------------------------------------------------------------------
__global__ __launch_bounds__(256) void softmax_rows(
    float* __restrict__ S, f16* __restrict__ P)
{
    const long long row = blockIdx.x;
    float* sr = S + row * 2048;
    f16*   pr = P + row * 2048;
    const int t = threadIdx.x;
    f32x4 v0 = ((f32x4*)sr)[t];
    f32x4 v1 = ((f32x4*)sr)[t + 256];
    float m = fmaxf(fmaxf(fmaxf(v0[0], v0[1]), fmaxf(v0[2], v0[3])),
                    fmaxf(fmaxf(v1[0], v1[1]), fmaxf(v1[2], v1[3])));
#pragma unroll
    for (int off = 32; off; off >>= 1) m = fmaxf(m, __shfl_xor(m, off));
    __shared__ float redm[4], reds[4];
    if ((t & 63) == 0) redm[t >> 6] = m;
    __syncthreads();
    m = fmaxf(fmaxf(redm[0], redm[1]), fmaxf(redm[2], redm[3]));
    float s = 0.f;
#pragma unroll
    for (int j = 0; j < 4; j++) { v0[j] = __expf(v0[j] - m); s += v0[j]; }
#pragma unroll
    for (int j = 0; j < 4; j++) { v1[j] = __expf(v1[j] - m); s += v1[j]; }
#pragma unroll
    for (int off = 32; off; off >>= 1) s += __shfl_xor(s, off);
    if ((t & 63) == 0) reds[t >> 6] = s;
    __syncthreads();
    s = reds[0] + reds[1] + reds[2] + reds[3];
    const float inv = 1.f / s;
#pragma unroll
    for (int j = 0; j < 4; j++) { v0[j] *= inv; v1[j] *= inv; }
    ((f32x4*)sr)[t]       = v0;
    ((f32x4*)sr)[t + 256] = v1;
    f16x4 p0 = { (f16)v0[0], (f16)v0[1], (f16)v0[2], (f16)v0[3] };
    f16x4 p1 = { (f16)v1[0], (f16)v1[1], (f16)v1[2], (f16)v1[3] };
    ((f16x4*)pr)[t]       = p0;
    ((f16x4*)pr)[t + 256] = p1;
}

// ---------------------------------------------------------------------------
extern "C" void kernel_launch(void* const* d_in, const int* in_sizes, int n_in,
                              void* d_out, int out_size, void* d_ws, size_t ws_size,
                              hipStream_t stream)
{
    const int B = 8, QL = 2048, KL = 2048, D = 1024;
    const long long BT = (long long)B * QL;           // 16384 tokens

    const float* k_in = (const float*)d_in[0];
    const float* q_in = (const float*)d_in[1];
    const float* Wk   = (const float*)d_in[2];
    const float* bk   = (const float*)d_in[3];
    const float* Wq   = (const float*)d_in[4];
    const float* bq   = (const float*)d_in[5];
    const float* Wb   = (const float*)d_in[6];
    const float* Wp   = (const float*)d_in[7];
    const float* bp   = (const float*)d_in[8];

    float* out   = (float*)d_out;                     // [8,2048,1024]
    float* score = out + BT * D;                      // [8,2048,2048]

    f16* w = (f16*)d_ws;
    f16* k_h   = w;  w += BT * D;
    f16* q_h   = w;  w += BT * D;
    f16* kx_h  = w;  w += BT * D;
    f16* kxT   = w;  w += (long long)B * D * KL;
    f16* qw_h  = w;  w += BT * D;
    f16* oa_h  = w;  w += BT * D;
    f16* P_h   = w;  w += (long long)B * QL * KL;
    f16* Wk_h  = w;  w += D * D;
    f16* WqT   = w;  w += D * D;
    f16* WbT   = w;  w += D * D;
    f16* Wp_h  = w;  w += D * D;
    f16* WcT   = w;  w += D * D;
    float* bc  = (float*)w;                           // 1024 f32

    dim3 b256(256);
    dim3 tb(32, 8);

    // fp32 -> fp16 conversions
    conv_f32_f16<<<(int)(BT * D / 4 / 256), b256, 0, stream>>>(k_in, k_h, BT * D / 4);
    conv_f32_f16<<<(int)(BT * D / 4 / 256), b256, 0, stream>>>(q_in, q_h, BT * D / 4);
    conv_f32_f16<<<D * D / 4 / 256, b256, 0, stream>>>(Wk, Wk_h, D * D / 4);
    conv_f32_f16<<<D * D / 4 / 256, b256, 0, stream>>>(Wp, Wp_h, D * D / 4);
    // transposed fp16 weights:  WqT[c][d] = Wq[d][c],  WbT[e][d] = W_bil[d][e]
    transpose_f16<float><<<dim3(32, 32, 1), tb, 0, stream>>>(Wq, WqT, D, D, 0, 0);
    transpose_f16<float><<<dim3(32, 32, 1), tb, 0, stream>>>(Wb, WbT, D, D, 0, 0);
    // folded bias: bc[e] = sum_d bq[d] * W_bil[d][e]
    bcomb_kernel<<<D, b256, 0, stream>>>(bq, WbT, bc);
    // folded weight: WcT[e][c] = sum_d W_bil[d][e] * Wq[d][c]  (= (Wq^T W_bil)^T)
    gemm_bt<true, false><<<dim3(8, 8, 1), b256, 0, stream>>>(
        WbT, WqT, nullptr, WcT, D, D, D, 0, 0, 0);
    // kx = k @ Wk^T + bk
    gemm_bt<true, true><<<dim3(8, 128, 1), b256, 0, stream>>>(
        k_h, Wk_h, bk, kx_h, (int)BT, D, D, 0, 0, 0);
    // qw = q @ Wc + bc
    gemm_bt<true, true><<<dim3(8, 128, 1), b256, 0, stream>>>(
        q_h, WcT, bc, qw_h, (int)BT, D, D, 0, 0, 0);
    // kxT[b][d][t] = kx[b][t][d]
    transpose_f16<f16><<<dim3(D / 32, KL / 32, B), tb, 0, stream>>>(
        kx_h, kxT, KL, D, (long long)KL * D, (long long)D * KL);
    // S = qw @ kx^T  (raw logits straight into d_out score region, fp32)
    gemm_bt<false, false><<<dim3(16, 16, 8), b256, 0, stream>>>(
        qw_h, kx_h, nullptr, score, QL, KL, D,
        (long long)QL * D, (long long)KL * D, (long long)QL * KL);
    // softmax in place + fp16 P for PV
    softmax_rows<<<B * QL, b256, 0, stream>>>(score, P_h);
    // out_attn = P @ kx   (via kxT, bt-form)
    gemm_bt<true, false><<<dim3(8, 16, 8), b256, 0, stream>>>(
        P_h, kxT, nullptr, oa_h, QL, D, KL,
        (long long)QL * KL, (long long)D * KL, (long long)QL * D);
    // out = out_attn @ Wp^T + bp
    gemm_bt<false, true><<<dim3(8, 128, 1), b256, 0, stream>>>(
        oa_h, Wp_h, bp, out, (int)BT, D, D, 0, 0, 0);
}

// Round 5
// 687.602 us; speedup vs baseline: 1.2027x; 1.1654x over previous
//
#include <hip/hip_runtime.h>
#include <hip/hip_bf16.h>

typedef unsigned short u16;
typedef unsigned int   u32;
typedef _Float16       f16;
typedef __attribute__((ext_vector_type(4))) float f32x4;
typedef __attribute__((ext_vector_type(8))) f16  f16x8;
typedef __attribute__((ext_vector_type(4))) f16  f16x4;

#define GLOAD_LDS16(gsrc, ldst)                                              \
    __builtin_amdgcn_global_load_lds(                                        \
        (const __attribute__((address_space(1))) void*)(gsrc),               \
        (__attribute__((address_space(3))) void*)(ldst), 16, 0, 0)

#define MFMA16(a, b, c) __builtin_amdgcn_mfma_f32_16x16x32_f16((a), (b), (c), 0, 0, 0)

// ---------------------------------------------------------------------------
// fp32 -> fp16 vectorized conversion
// ---------------------------------------------------------------------------
__global__ __launch_bounds__(256) void conv_f32_f16(
    const float* __restrict__ in, f16* __restrict__ out, long long n4)
{
    long long i = (long long)blockIdx.x * 256 + threadIdx.x;
    if (i >= n4) return;
    f32x4 v = ((const f32x4*)in)[i];
    f16x4 o = { (f16)v[0], (f16)v[1], (f16)v[2], (f16)v[3] };
    ((f16x4*)out)[i] = o;
}

// ---------------------------------------------------------------------------
// transpose (+convert) -> fp16.  in: [rows][cols], out: [cols][rows]
// block (32,8), grid (cols/32, rows/32, batch)
// ---------------------------------------------------------------------------
template<typename TIN>
__global__ __launch_bounds__(256) void transpose_f16(
    const TIN* __restrict__ in, f16* __restrict__ out,
    int rows, int cols, long long sIn, long long sOut)
{
    __shared__ f16 tile[32][33];
    const int bz = blockIdx.z;
    const TIN* ib = in + sIn * bz;
    f16* ob = out + sOut * bz;
    const int c0 = blockIdx.x * 32, r0 = blockIdx.y * 32;
    const int tx = threadIdx.x, ty = threadIdx.y;
#pragma unroll
    for (int i = 0; i < 4; i++) {
        int r = ty + i * 8;
        TIN v = ib[(long long)(r0 + r) * cols + c0 + tx];
        tile[r][tx] = (f16)v;
    }
    __syncthreads();
#pragma unroll
    for (int i = 0; i < 4; i++) {
        int r = ty + i * 8;
        ob[(long long)(c0 + r) * rows + r0 + tx] = tile[tx][r];
    }
}

// ---------------------------------------------------------------------------
// b_comb[e] = sum_d bq[d] * W_bil[d][e]   (uses transposed fp16 W_bil)
// ---------------------------------------------------------------------------
__global__ __launch_bounds__(256) void bcomb_kernel(
    const float* __restrict__ bq, const f16* __restrict__ WbT, float* __restrict__ bc)
{
    const int e = blockIdx.x;
    const f16* row = WbT + (long long)e * 1024;
    const int t = threadIdx.x;
    float s = 0.f;
    for (int d = t; d < 1024; d += 256) s += bq[d] * (float)row[d];
#pragma unroll
    for (int off = 32; off; off >>= 1) s += __shfl_xor(s, off);
    __shared__ float red[4];
    if ((t & 63) == 0) red[t >> 6] = s;
    __syncthreads();
    if (t == 0) bc[e] = red[0] + red[1] + red[2] + red[3];
}

// ---------------------------------------------------------------------------
// GEMM  C[M,N] = A[M,K] @ B[N,K]^T (+ bias[N]).  fp16 in, f32 accum.
// 256x256 8-phase template (T2+T3+T4+T5): BK=64, 512 threads (8 waves 2Mx4N,
// each owns 128x64 of C). LDS 128 KiB: [2 parity][256][64] f16 for A and B.
// Per K-tile, 4 phases: {ds_read frags | stage 1 half-tile} -> s_barrier ->
// setprio(1) 16 MFMA setprio(0) -> s_barrier. Counted vmcnt(2) once per
// K-tile (never 0 in main loop). T2: 16B-slot XOR row&7 swizzle, applied as
// inverse-swizzled GLOBAL source + swizzled ds_read (LDS dest stays linear).
// grid (N/256, M/256, batch). K % 128 == 0.
// ---------------------------------------------------------------------------
template<bool OUT_F16, bool HAS_BIAS>
__global__ __launch_bounds__(512) void gemm_bt256(
    const f16* __restrict__ A, const f16* __restrict__ B,
    const float* __restrict__ bias, void* __restrict__ Cout,
    int M, int N, int K, int NT,
    long long sAb, long long sBb, long long sCb)
{
    __shared__ f16 Al[2][256][64];
    __shared__ f16 Bl[2][256][64];
    const int bz = blockIdx.z;
    const f16* Ab = A + sAb * bz + (long long)blockIdx.y * 256 * K;
    const f16* Bb = B + sBb * bz + (long long)blockIdx.x * 256 * K;
    const int tid  = threadIdx.x;
    const int lane = tid & 63;
    const int wid  = tid >> 6;      // 0..7
    const int wr   = wid >> 2;      // 0..1  (M half)
    const int wcn  = wid & 3;       // 0..3  (N quarter)
    const int fr   = lane & 15;
    const int kq   = lane >> 4;     // 0..3
    const int sx   = lane & 7;      // read-side swizzle key (== fr&7)

    // --- staging params: 1024 16B-chunks per half-tile, thread does 2.
    // chunk c -> row (c>>3) of the 128-row half, slot c&7; global slot is
    // (c&7) ^ (row&7)  (involution; read side applies the same XOR).
    const int c0 = tid, c1 = tid + 512;
    const long long ga0 = (long long)(c0 >> 3) * K + (((c0 & 7) ^ ((c0 >> 3) & 7)) * 8);
    const long long ga1 = (long long)(c1 >> 3) * K + (((c1 & 7) ^ ((c1 >> 3) & 7)) * 8);
    const long long gh  = (long long)128 * K;      // global half stride
    const int ld0 = c0 * 8;                        // f16 offset within half
    const int ld1 = c1 * 8;
    f16* AlF = &Al[0][0][0];
    f16* BlF = &Bl[0][0][0];

    // --- read-side offsets (f16): row*64 + swizzled-slot*8
    const int aBase = (wr * 128 + fr) * 64;
    const int bBase = (wcn * 64 + fr) * 64;
    const int s0 = ((0 * 4 + kq) ^ sx) * 8;        // k-step 0 slot
    const int s1 = ((1 * 4 + kq) ^ sx) * 8;        // k-step 1 slot

    f32x4 acc[8][4];
#pragma unroll
    for (int m = 0; m < 8; m++)
#pragma unroll
        for (int n = 0; n < 4; n++) acc[m][n] = (f32x4){0.f, 0.f, 0.f, 0.f};

    auto stageA = [&](int par, int half, int kt) {
        GLOAD_LDS16(Ab + half * gh + kt * 64 + ga0, AlF + par * 16384 + half * 8192 + ld0);
        GLOAD_LDS16(Ab + half * gh + kt * 64 + ga1, AlF + par * 16384 + half * 8192 + ld1);
    };
    auto stageB = [&](int par, int half, int kt) {
        GLOAD_LDS16(Bb + half * gh + kt * 64 + ga0, BlF + par * 16384 + half * 8192 + ld0);
        GLOAD_LDS16(Bb + half * gh + kt * 64 + ga1, BlF + par * 16384 + half * 8192 + ld1);
    };

    // one K-tile = 4 phases; stages K-tile ktn into parity par^1
    auto ktile = [&](int par, int kt, int ktn) {
        const int np = par ^ 1;
        const f16* Ap = AlF + par * 16384;
        const f16* Bp = BlF + par * 16384;
        f16x8 bf_[4][2];
        // ---- phase 0: stage -> vmcnt(2) -> barrier -> 12 ds_reads -> MFMA
        stageA(np, 0, ktn);
        asm volatile("s_waitcnt vmcnt(2)" ::: "memory");
        __builtin_amdgcn_s_barrier();
        __builtin_amdgcn_sched_barrier(0);
#pragma unroll
        for (int nf = 0; nf < 4; nf++) {
            bf_[nf][0] = *(const f16x8*)&Bp[bBase + nf * 1024 + s0];
            bf_[nf][1] = *(const f16x8*)&Bp[bBase + nf * 1024 + s1];
        }
        {
            f16x8 a00 = *(const f16x8*)&Ap[aBase + 0 * 1024 + s0];
            f16x8 a01 = *(const f16x8*)&Ap[aBase + 0 * 1024 + s1];
            f16x8 a10 = *(const f16x8*)&Ap[aBase + 1 * 1024 + s0];
            f16x8 a11 = *(const f16x8*)&Ap[aBase + 1 * 1024 + s1];
            __builtin_amdgcn_s_setprio(1);
#pragma unroll
            for (int nf = 0; nf < 4; nf++) {
                acc[0][nf] = MFMA16(a00, bf_[nf][0], acc[0][nf]);
                acc[0][nf] = MFMA16(a01, bf_[nf][1], acc[0][nf]);
                acc[1][nf] = MFMA16(a10, bf_[nf][0], acc[1][nf]);
                acc[1][nf] = MFMA16(a11, bf_[nf][1], acc[1][nf]);
            }
            __builtin_amdgcn_s_setprio(0);
        }
        __builtin_amdgcn_s_barrier();
        __builtin_amdgcn_sched_barrier(0);
        // ---- phases 1..3: ds_reads issued pre-barrier (buffer already stable)
#pragma unroll
        for (int p4 = 1; p4 < 4; p4++) {
            const int m0 = 2 * p4;
            f16x8 a00 = *(const f16x8*)&Ap[aBase + (m0    ) * 1024 + s0];
            f16x8 a01 = *(const f16x8*)&Ap[aBase + (m0    ) * 1024 + s1];
            f16x8 a10 = *(const f16x8*)&Ap[aBase + (m0 + 1) * 1024 + s0];
            f16x8 a11 = *(const f16x8*)&Ap[aBase + (m0 + 1) * 1024 + s1];
            if (p4 == 1)      stageA(np, 1, ktn);
            else if (p4 == 2) stageB(np, 0, ktn);
            else              stageB(np, 1, ktn);
            __builtin_amdgcn_s_barrier();
            __builtin_amdgcn_sched_barrier(0);
            __builtin_amdgcn_s_setprio(1);
#pragma unroll
            for (int nf = 0; nf < 4; nf++) {
                acc[m0    ][nf] = MFMA16(a00, bf_[nf][0], acc[m0    ][nf]);
                acc[m0    ][nf] = MFMA16(a01, bf_[nf][1], acc[m0    ][nf]);
                acc[m0 + 1][nf] = MFMA16(a10, bf_[nf][0], acc[m0 + 1][nf]);
                acc[m0 + 1][nf] = MFMA16(a11, bf_[nf][1], acc[m0 + 1][nf]);
            }
            __builtin_amdgcn_s_setprio(0);
            __builtin_amdgcn_s_barrier();
            __builtin_amdgcn_sched_barrier(0);
        }
    };

    // prologue: stage K-tile 0 into parity 0
    stageA(0, 0, 0); stageA(0, 1, 0); stageB(0, 0, 0); stageB(0, 1, 0);

    for (int kt = 0; kt < NT; kt += 2) {
        ktile(0, kt, kt + 1);
        ktile(1, kt + 1, (kt + 2 == NT) ? 0 : kt + 2);   // last prefetch wraps (harmless)
    }

    // epilogue
    const long long crow0 = (long long)blockIdx.y * 256 + wr * 128;
    const int ccol0 = blockIdx.x * 256 + wcn * 64;
#pragma unroll
    for (int mf = 0; mf < 8; mf++) {
#pragma unroll
        for (int nf = 0; nf < 4; nf++) {
            const int col = ccol0 + nf * 16 + fr;
            float bv = 0.f;
            if constexpr (HAS_BIAS) bv = bias[col];
#pragma unroll
            for (int i = 0; i < 4; i++) {
                const long long r = crow0 + mf * 16 + kq * 4 + i;
                const float val = acc[mf][nf][i] + bv;
                if constexpr (OUT_F16)
                    ((f16*)Cout)[sCb * bz + r * N + col] = (f16)val;
                else
                    ((float*)Cout)[sCb * bz + r * N + col] = val;
            }
        }
    }
}

// ---------------------------------------------------------------------------
// Row softmax over 2048 cols, in-place fp32 + fp16 copy. 256 thr, 1 block/row.
// ---------------------------------------------------------------------------
__global__ __launch_bounds__(256) void softmax_rows(
    float* __restrict__ S, f16* __restrict__ P)
{
    const long long row = blockIdx.x;
    float* sr = S + row * 2048;
    f16*   pr = P + row * 2048;
    const int t = threadIdx.x;
    f32x4 v0 = ((f32x4*)sr)[t];
    f32x4 v1 = ((f32x4*)sr)[t + 256];
    float m = fmaxf(fmaxf(fmaxf(v0[0], v0[1]), fmaxf(v0[2], v0[3])),
                    fmaxf(fmaxf(v1[0], v1[1]), fmaxf(v1[2], v1[3])));
#pragma unroll
    for (int off = 32; off; off >>= 1) m = fmaxf(m, __shfl_xor(m, off));
    __shared__ float redm[4], reds[4];
    if ((t & 63) == 0) redm[t >> 6] = m;
    __syncthreads();
    m = fmaxf(fmaxf(redm[0], redm[1]), fmaxf(redm[2], redm[3]));
    float s = 0.f;
#pragma unroll
    for (int j = 0; j < 4; j++) { v0[j] = __expf(v0[j] - m); s += v0[j]; }
#pragma unroll
    for (int j = 0; j < 4; j++) { v1[j] = __expf(v1[j] - m); s += v1[j]; }
#pragma unroll
    for (int off = 32; off; off >>= 1) s += __shfl_xor(s, off);
    if ((t & 63) == 0) reds[t >> 6] = s;
    __syncthreads();
    s = reds[0] + reds[1] + reds[2] + reds[3];
    const float inv = 1.f / s;
#pragma unroll
    for (int j = 0; j < 4; j++) { v0[j] *= inv; v1[j] *= inv; }
    ((f32x4*)sr)[t]       = v0;
    ((f32x4*)sr)[t + 256] = v1;
    f16x4 p0 = { (f16)v0[0], (f16)v0[1], (f16)v0[2], (f16)v0[3] };
    f16x4 p1 = { (f16)v1[0], (f16)v1[1], (f16)v1[2], (f16)v1[3] };
    ((f16x4*)pr)[t]       = p0;
    ((f16x4*)pr)[t + 256] = p1;
}

// ---------------------------------------------------------------------------
extern "C" void kernel_launch(void* const* d_in, const int* in_sizes, int n_in,
                              void* d_out, int out_size, void* d_ws, size_t ws_size,
                              hipStream_t stream)
{
    const int B = 8, QL = 2048, KL = 2048, D = 1024;
    const long long BT = (long long)B * QL;           // 16384 tokens

    const float* k_in = (const float*)d_in[0];
    const float* q_in = (const float*)d_in[1];
    const float* Wk   = (const float*)d_in[2];
    const float* bk   = (const float*)d_in[3];
    const float* Wq   = (const float*)d_in[4];
    const float* bq   = (const float*)d_in[5];
    const float* Wb   = (const float*)d_in[6];
    const float* Wp   = (const float*)d_in[7];
    const float* bp   = (const float*)d_in[8];

    float* out   = (float*)d_out;                     // [8,2048,1024]
    float* score = out + BT * D;                      // [8,2048,2048]

    f16* w = (f16*)d_ws;
    f16* k_h   = w;  w += BT * D;
    f16* q_h   = w;  w += BT * D;
    f16* kx_h  = w;  w += BT * D;
    f16* kxT   = w;  w += (long long)B * D * KL;
    f16* qw_h  = w;  w += BT * D;
    f16* oa_h  = w;  w += BT * D;
    f16* P_h   = w;  w += (long long)B * QL * KL;
    f16* Wk_h  = w;  w += D * D;
    f16* WqT   = w;  w += D * D;
    f16* WbT   = w;  w += D * D;
    f16* Wp_h  = w;  w += D * D;
    f16* WcT   = w;  w += D * D;
    float* bc  = (float*)w;                           // 1024 f32

    dim3 b256(256);
    dim3 b512(512);
    dim3 tb(32, 8);

    // fp32 -> fp16 conversions
    conv_f32_f16<<<(int)(BT * D / 4 / 256), b256, 0, stream>>>(k_in, k_h, BT * D / 4);
    conv_f32_f16<<<(int)(BT * D / 4 / 256), b256, 0, stream>>>(q_in, q_h, BT * D / 4);
    conv_f32_f16<<<D * D / 4 / 256, b256, 0, stream>>>(Wk, Wk_h, D * D / 4);
    conv_f32_f16<<<D * D / 4 / 256, b256, 0, stream>>>(Wp, Wp_h, D * D / 4);
    // transposed fp16 weights:  WqT[c][d] = Wq[d][c],  WbT[e][d] = W_bil[d][e]
    transpose_f16<float><<<dim3(32, 32, 1), tb, 0, stream>>>(Wq, WqT, D, D, 0, 0);
    transpose_f16<float><<<dim3(32, 32, 1), tb, 0, stream>>>(Wb, WbT, D, D, 0, 0);
    // folded bias: bc[e] = sum_d bq[d] * W_bil[d][e]
    bcomb_kernel<<<D, b256, 0, stream>>>(bq, WbT, bc);
    // folded weight: WcT[e][c] = sum_d W_bil[d][e] * Wq[d][c]  (= (Wq^T W_bil)^T)
    gemm_bt256<true, false><<<dim3(4, 4, 1), b512, 0, stream>>>(
        WbT, WqT, nullptr, WcT, D, D, D, D / 64, 0, 0, 0);
    // kx = k @ Wk^T + bk
    gemm_bt256<true, true><<<dim3(4, 64, 1), b512, 0, stream>>>(
        k_h, Wk_h, bk, kx_h, (int)BT, D, D, D / 64, 0, 0, 0);
    // qw = q @ Wc + bc
    gemm_bt256<true, true><<<dim3(4, 64, 1), b512, 0, stream>>>(
        q_h, WcT, bc, qw_h, (int)BT, D, D, D / 64, 0, 0, 0);
    // kxT[b][d][t] = kx[b][t][d]
    transpose_f16<f16><<<dim3(D / 32, KL / 32, B), tb, 0, stream>>>(
        kx_h, kxT, KL, D, (long long)KL * D, (long long)D * KL);
    // S = qw @ kx^T  (raw logits straight into d_out score region, fp32)
    gemm_bt256<false, false><<<dim3(8, 8, 8), b512, 0, stream>>>(
        qw_h, kx_h, nullptr, score, QL, KL, D, D / 64,
        (long long)QL * D, (long long)KL * D, (long long)QL * KL);
    // softmax in place + fp16 P for PV
    softmax_rows<<<B * QL, b256, 0, stream>>>(score, P_h);
    // out_attn = P @ kx   (via kxT, bt-form)
    gemm_bt256<true, false><<<dim3(4, 8, 8), b512, 0, stream>>>(
        P_h, kxT, nullptr, oa_h, QL, D, KL, KL / 64,
        (long long)QL * KL, (long long)D * KL, (long long)QL * D);
    // out = out_attn @ Wp^T + bp
    gemm_bt256<false, true><<<dim3(4, 64, 1), b512, 0, stream>>>(
        oa_h, Wp_h, bp, out, (int)BT, D, D, D / 64, 0, 0, 0);
}

// Round 6
// 664.835 us; speedup vs baseline: 1.2439x; 1.0342x over previous
//
#include <hip/hip_runtime.h>
#include <hip/hip_bf16.h>

typedef unsigned short u16;
typedef unsigned int   u32;
typedef _Float16       f16;
typedef __attribute__((ext_vector_type(4))) float f32x4;
typedef __attribute__((ext_vector_type(8))) f16  f16x8;
typedef __attribute__((ext_vector_type(4))) f16  f16x4;

#define GLOAD_LDS16(gsrc, ldst)                                              \
    __builtin_amdgcn_global_load_lds(                                        \
        (const __attribute__((address_space(1))) void*)(gsrc),               \
        (__attribute__((address_space(3))) void*)(ldst), 16, 0, 0)

#define MFMA16(a, b, c) __builtin_amdgcn_mfma_f32_16x16x32_f16((a), (b), (c), 0, 0, 0)

// ---------------------------------------------------------------------------
// fp32 -> fp16 vectorized conversion
// ---------------------------------------------------------------------------
__global__ __launch_bounds__(256) void conv_f32_f16(
    const float* __restrict__ in, f16* __restrict__ out, long long n4)
{
    long long i = (long long)blockIdx.x * 256 + threadIdx.x;
    if (i >= n4) return;
    f32x4 v = ((const f32x4*)in)[i];
    f16x4 o = { (f16)v[0], (f16)v[1], (f16)v[2], (f16)v[3] };
    ((f16x4*)out)[i] = o;
}

// ---------------------------------------------------------------------------
// transpose (+convert) -> fp16.  in: [rows][cols], out: [cols][rows]
// block (32,8), grid (cols/32, rows/32, batch)
// ---------------------------------------------------------------------------
template<typename TIN>
__global__ __launch_bounds__(256) void transpose_f16(
    const TIN* __restrict__ in, f16* __restrict__ out,
    int rows, int cols, long long sIn, long long sOut)
{
    __shared__ f16 tile[32][33];
    const int bz = blockIdx.z;
    const TIN* ib = in + sIn * bz;
    f16* ob = out + sOut * bz;
    const int c0 = blockIdx.x * 32, r0 = blockIdx.y * 32;
    const int tx = threadIdx.x, ty = threadIdx.y;
#pragma unroll
    for (int i = 0; i < 4; i++) {
        int r = ty + i * 8;
        TIN v = ib[(long long)(r0 + r) * cols + c0 + tx];
        tile[r][tx] = (f16)v;
    }
    __syncthreads();
#pragma unroll
    for (int i = 0; i < 4; i++) {
        int r = ty + i * 8;
        ob[(long long)(c0 + r) * rows + r0 + tx] = tile[tx][r];
    }
}

// ---------------------------------------------------------------------------
// b_comb[e] = sum_d bq[d] * W_bil[d][e]   (uses transposed fp16 W_bil)
// ---------------------------------------------------------------------------
__global__ __launch_bounds__(256) void bcomb_kernel(
    const float* __restrict__ bq, const f16* __restrict__ WbT, float* __restrict__ bc)
{
    const int e = blockIdx.x;
    const f16* row = WbT + (long long)e * 1024;
    const int t = threadIdx.x;
    float s = 0.f;
    for (int d = t; d < 1024; d += 256) s += bq[d] * (float)row[d];
#pragma unroll
    for (int off = 32; off; off >>= 1) s += __shfl_xor(s, off);
    __shared__ float red[4];
    if ((t & 63) == 0) red[t >> 6] = s;
    __syncthreads();
    if (t == 0) bc[e] = red[0] + red[1] + red[2] + red[3];
}

// ---------------------------------------------------------------------------
// GEMM  C[M,N] = A[M,K] @ B[N,K]^T (+ bias[N]).  fp16 in, f32 accum.
// 256x256 8-phase template (T1+T2+T3+T4+T5): BK=64, 512 threads (8 waves
// 2Mx4N, each owns 128x64 of C). LDS 128 KiB: [2 parity][256][64] f16 A,B.
// K-tile = 4 phases x {ds_read frags | stage} -> s_barrier -> setprio(1)
// 16 MFMA setprio(0) -> s_barrier.  All 8 next-tile loads issued in phases
// 0-1 (A then B); single counted vmcnt(4) at phase 0 => last-issued loads
// get ~3 phases of MFMA cover before their consumer waits.  T2: 16B-slot
// XOR row&7 swizzle via inverse-swizzled GLOBAL source + swizzled ds_read
// (LDS dest linear).  T1: bijective XCD-chunk swizzle of linearized blockIdx
// (requires nwg % 8 == 0).  grid (N/256, M/256, batch), K % 128 == 0.
// ---------------------------------------------------------------------------
template<bool OUT_F16, bool HAS_BIAS>
__global__ __launch_bounds__(512) void gemm_bt256(
    const f16* __restrict__ A, const f16* __restrict__ B,
    const float* __restrict__ bias, void* __restrict__ Cout,
    int M, int N, int K, int NT,
    long long sAb, long long sBb, long long sCb)
{
    __shared__ f16 Al[2][256][64];
    __shared__ f16 Bl[2][256][64];

    // --- T1: XCD-aware bijective block swizzle (nwg multiple of 8)
    const int gx = gridDim.x, gy = gridDim.y;
    const int nwg = gx * gy * gridDim.z;
    const int lin = (blockIdx.z * gy + blockIdx.y) * gx + blockIdx.x;
    const int swz = (lin & 7) * (nwg >> 3) + (lin >> 3);
    const int bx = swz % gx;
    const int by = (swz / gx) % gy;
    const int bz = swz / (gx * gy);

    const f16* Ab = A + sAb * bz + (long long)by * 256 * K;
    const f16* Bb = B + sBb * bz + (long long)bx * 256 * K;
    const int tid  = threadIdx.x;
    const int lane = tid & 63;
    const int wid  = tid >> 6;      // 0..7
    const int wr   = wid >> 2;      // 0..1  (M half)
    const int wcn  = wid & 3;       // 0..3  (N quarter)
    const int fr   = lane & 15;
    const int kq   = lane >> 4;     // 0..3
    const int sx   = lane & 7;      // read-side swizzle key (== fr&7)

    // --- staging params: 1024 16B-chunks per half-tile, thread does 2.
    // chunk c -> row (c>>3) of the 128-row half, slot c&7; global slot is
    // (c&7) ^ (row&7)  (involution; read side applies the same XOR).
    const int c0 = tid, c1 = tid + 512;
    const long long ga0 = (long long)(c0 >> 3) * K + (((c0 & 7) ^ ((c0 >> 3) & 7)) * 8);
    const long long ga1 = (long long)(c1 >> 3) * K + (((c1 & 7) ^ ((c1 >> 3) & 7)) * 8);
    const long long gh  = (long long)128 * K;      // global half stride
    const int ld0 = c0 * 8;                        // f16 offset within half
    const int ld1 = c1 * 8;
    f16* AlF = &Al[0][0][0];
    f16* BlF = &Bl[0][0][0];

    // --- read-side offsets (f16): row*64 + swizzled-slot*8
    const int aBase = (wr * 128 + fr) * 64;
    const int bBase = (wcn * 64 + fr) * 64;
    const int s0 = ((0 * 4 + kq) ^ sx) * 8;        // k-step 0 slot
    const int s1 = ((1 * 4 + kq) ^ sx) * 8;        // k-step 1 slot

    f32x4 acc[8][4];
#pragma unroll
    for (int m = 0; m < 8; m++)
#pragma unroll
        for (int n = 0; n < 4; n++) acc[m][n] = (f32x4){0.f, 0.f, 0.f, 0.f};

    auto stageA = [&](int par, int half, int kt) {
        GLOAD_LDS16(Ab + half * gh + kt * 64 + ga0, AlF + par * 16384 + half * 8192 + ld0);
        GLOAD_LDS16(Ab + half * gh + kt * 64 + ga1, AlF + par * 16384 + half * 8192 + ld1);
    };
    auto stageB = [&](int par, int half, int kt) {
        GLOAD_LDS16(Bb + half * gh + kt * 64 + ga0, BlF + par * 16384 + half * 8192 + ld0);
        GLOAD_LDS16(Bb + half * gh + kt * 64 + ga1, BlF + par * 16384 + half * 8192 + ld1);
    };

    // one K-tile = 4 phases; stages K-tile ktn into parity par^1.
    // A-loads issued phase 0, B-loads phase 1 -> waited 3-4 phases later.
    auto ktile = [&](int par, int kt, int ktn) {
        const int np = par ^ 1;
        const f16* Ap = AlF + par * 16384;
        const f16* Bp = BlF + par * 16384;
        f16x8 bf_[4][2];
        // ---- phase 0: issue A-stages -> vmcnt(4) -> barrier -> reads -> MFMA
        stageA(np, 0, ktn);
        stageA(np, 1, ktn);
        asm volatile("s_waitcnt vmcnt(4)" ::: "memory");
        __builtin_amdgcn_s_barrier();
        __builtin_amdgcn_sched_barrier(0);
#pragma unroll
        for (int nf = 0; nf < 4; nf++) {
            bf_[nf][0] = *(const f16x8*)&Bp[bBase + nf * 1024 + s0];
            bf_[nf][1] = *(const f16x8*)&Bp[bBase + nf * 1024 + s1];
        }
        {
            f16x8 a00 = *(const f16x8*)&Ap[aBase + 0 * 1024 + s0];
            f16x8 a01 = *(const f16x8*)&Ap[aBase + 0 * 1024 + s1];
            f16x8 a10 = *(const f16x8*)&Ap[aBase + 1 * 1024 + s0];
            f16x8 a11 = *(const f16x8*)&Ap[aBase + 1 * 1024 + s1];
            __builtin_amdgcn_s_setprio(1);
#pragma unroll
            for (int nf = 0; nf < 4; nf++) {
                acc[0][nf] = MFMA16(a00, bf_[nf][0], acc[0][nf]);
                acc[0][nf] = MFMA16(a01, bf_[nf][1], acc[0][nf]);
                acc[1][nf] = MFMA16(a10, bf_[nf][0], acc[1][nf]);
                acc[1][nf] = MFMA16(a11, bf_[nf][1], acc[1][nf]);
            }
            __builtin_amdgcn_s_setprio(0);
        }
        __builtin_amdgcn_s_barrier();
        __builtin_amdgcn_sched_barrier(0);
        // ---- phases 1..3: ds_reads issued pre-barrier (buffer stable);
        //      phase 1 issues the B-stages.
#pragma unroll
        for (int p4 = 1; p4 < 4; p4++) {
            const int m0 = 2 * p4;
            f16x8 a00 = *(const f16x8*)&Ap[aBase + (m0    ) * 1024 + s0];
            f16x8 a01 = *(const f16x8*)&Ap[aBase + (m0    ) * 1024 + s1];
            f16x8 a10 = *(const f16x8*)&Ap[aBase + (m0 + 1) * 1024 + s0];
            f16x8 a11 = *(const f16x8*)&Ap[aBase + (m0 + 1) * 1024 + s1];
            if (p4 == 1) {
                stageB(np, 0, ktn);
                stageB(np, 1, ktn);
            }
            __builtin_amdgcn_s_barrier();
            __builtin_amdgcn_sched_barrier(0);
            __builtin_amdgcn_s_setprio(1);
#pragma unroll
            for (int nf = 0; nf < 4; nf++) {
                acc[m0    ][nf] = MFMA16(a00, bf_[nf][0], acc[m0    ][nf]);
                acc[m0    ][nf] = MFMA16(a01, bf_[nf][1], acc[m0    ][nf]);
                acc[m0 + 1][nf] = MFMA16(a10, bf_[nf][0], acc[m0 + 1][nf]);
                acc[m0 + 1][nf] = MFMA16(a11, bf_[nf][1], acc[m0 + 1][nf]);
            }
            __builtin_amdgcn_s_setprio(0);
            __builtin_amdgcn_s_barrier();
            __builtin_amdgcn_sched_barrier(0);
        }
    };

    // prologue: stage K-tile 0 into parity 0
    stageA(0, 0, 0); stageA(0, 1, 0); stageB(0, 0, 0); stageB(0, 1, 0);

    for (int kt = 0; kt < NT; kt += 2) {
        ktile(0, kt, kt + 1);
        ktile(1, kt + 1, (kt + 2 == NT) ? 0 : kt + 2);   // last prefetch wraps (harmless)
    }

    // epilogue
    const long long crow0 = (long long)by * 256 + wr * 128;
    const int ccol0 = bx * 256 + wcn * 64;
#pragma unroll
    for (int mf = 0; mf < 8; mf++) {
#pragma unroll
        for (int nf = 0; nf < 4; nf++) {
            const int col = ccol0 + nf * 16 + fr;
            float bv = 0.f;
            if constexpr (HAS_BIAS) bv = bias[col];
#pragma unroll
            for (int i = 0; i < 4; i++) {
                const long long r = crow0 + mf * 16 + kq * 4 + i;
                const float val = acc[mf][nf][i] + bv;
                if constexpr (OUT_F16)
                    ((f16*)Cout)[sCb * bz + r * N + col] = (f16)val;
                else
                    ((float*)Cout)[sCb * bz + r * N + col] = val;
            }
        }
    }
}

// ---------------------------------------------------------------------------
// Row softmax over 2048 cols, in-place fp32 + fp16 copy. 256 thr, 1 block/row.
// ---------------------------------------------------------------------------
__global__ __launch_bounds__(256) void softmax_rows(
    float* __restrict__ S, f16* __restrict__ P)
{
    const long long row = blockIdx.x;
    float* sr = S + row * 2048;
    f16*   pr = P + row * 2048;
    const int t = threadIdx.x;
    f32x4 v0 = ((f32x4*)sr)[t];
    f32x4 v1 = ((f32x4*)sr)[t + 256];
    float m = fmaxf(fmaxf(fmaxf(v0[0], v0[1]), fmaxf(v0[2], v0[3])),
                    fmaxf(fmaxf(v1[0], v1[1]), fmaxf(v1[2], v1[3])));
#pragma unroll
    for (int off = 32; off; off >>= 1) m = fmaxf(m, __shfl_xor(m, off));
    __shared__ float redm[4], reds[4];
    if ((t & 63) == 0) redm[t >> 6] = m;
    __syncthreads();
    m = fmaxf(fmaxf(redm[0], redm[1]), fmaxf(redm[2], redm[3]));
    float s = 0.f;
#pragma unroll
    for (int j = 0; j < 4; j++) { v0[j] = __expf(v0[j] - m); s += v0[j]; }
#pragma unroll
    for (int j = 0; j < 4; j++) { v1[j] = __expf(v1[j] - m); s += v1[j]; }
#pragma unroll
    for (int off = 32; off; off >>= 1) s += __shfl_xor(s, off);
    if ((t & 63) == 0) reds[t >> 6] = s;
    __syncthreads();
    s = reds[0] + reds[1] + reds[2] + reds[3];
    const float inv = 1.f / s;
#pragma unroll
    for (int j = 0; j < 4; j++) { v0[j] *= inv; v1[j] *= inv; }
    ((f32x4*)sr)[t]       = v0;
    ((f32x4*)sr)[t + 256] = v1;
    f16x4 p0 = { (f16)v0[0], (f16)v0[1], (f16)v0[2], (f16)v0[3] };
    f16x4 p1 = { (f16)v1[0], (f16)v1[1], (f16)v1[2], (f16)v1[3] };
    ((f16x4*)pr)[t]       = p0;
    ((f16x4*)pr)[t + 256] = p1;
}

// ---------------------------------------------------------------------------
extern "C" void kernel_launch(void* const* d_in, const int* in_sizes, int n_in,
                              void* d_out, int out_size, void* d_ws, size_t ws_size,
                              hipStream_t stream)
{
    const int B = 8, QL = 2048, KL = 2048, D = 1024;
    const long long BT = (long long)B * QL;           // 16384 tokens

    const float* k_in = (const float*)d_in[0];
    const float* q_in = (const float*)d_in[1];
    const float* Wk   = (const float*)d_in[2];
    const float* bk   = (const float*)d_in[3];
    const float* Wq   = (const float*)d_in[4];
    const float* bq   = (const float*)d_in[5];
    const float* Wb   = (const float*)d_in[6];
    const float* Wp   = (const float*)d_in[7];
    const float* bp   = (const float*)d_in[8];

    float* out   = (float*)d_out;                     // [8,2048,1024]
    float* score = out + BT * D;                      // [8,2048,2048]

    f16* w = (f16*)d_ws;
    f16* k_h   = w;  w += BT * D;
    f16* q_h   = w;  w += BT * D;
    f16* kx_h  = w;  w += BT * D;
    f16* kxT   = w;  w += (long long)B * D * KL;
    f16* qw_h  = w;  w += BT * D;
    f16* oa_h  = w;  w += BT * D;
    f16* P_h   = w;  w += (long long)B * QL * KL;
    f16* Wk_h  = w;  w += D * D;
    f16* WqT   = w;  w += D * D;
    f16* WbT   = w;  w += D * D;
    f16* Wp_h  = w;  w += D * D;
    f16* WcT   = w;  w += D * D;
    float* bc  = (float*)w;                           // 1024 f32

    dim3 b256(256);
    dim3 b512(512);
    dim3 tb(32, 8);

    // fp32 -> fp16 conversions
    conv_f32_f16<<<(int)(BT * D / 4 / 256), b256, 0, stream>>>(k_in, k_h, BT * D / 4);
    conv_f32_f16<<<(int)(BT * D / 4 / 256), b256, 0, stream>>>(q_in, q_h, BT * D / 4);
    conv_f32_f16<<<D * D / 4 / 256, b256, 0, stream>>>(Wk, Wk_h, D * D / 4);
    conv_f32_f16<<<D * D / 4 / 256, b256, 0, stream>>>(Wp, Wp_h, D * D / 4);
    // transposed fp16 weights:  WqT[c][d] = Wq[d][c],  WbT[e][d] = W_bil[d][e]
    transpose_f16<float><<<dim3(32, 32, 1), tb, 0, stream>>>(Wq, WqT, D, D, 0, 0);
    transpose_f16<float><<<dim3(32, 32, 1), tb, 0, stream>>>(Wb, WbT, D, D, 0, 0);
    // folded bias: bc[e] = sum_d bq[d] * W_bil[d][e]
    bcomb_kernel<<<D, b256, 0, stream>>>(bq, WbT, bc);
    // folded weight: WcT[e][c] = sum_d W_bil[d][e] * Wq[d][c]  (= (Wq^T W_bil)^T)
    gemm_bt256<true, false><<<dim3(4, 4, 1), b512, 0, stream>>>(
        WbT, WqT, nullptr, WcT, D, D, D, D / 64, 0, 0, 0);
    // kx = k @ Wk^T + bk
    gemm_bt256<true, true><<<dim3(4, 64, 1), b512, 0, stream>>>(
        k_h, Wk_h, bk, kx_h, (int)BT, D, D, D / 64, 0, 0, 0);
    // qw = q @ Wc + bc
    gemm_bt256<true, true><<<dim3(4, 64, 1), b512, 0, stream>>>(
        q_h, WcT, bc, qw_h, (int)BT, D, D, D / 64, 0, 0, 0);
    // kxT[b][d][t] = kx[b][t][d]
    transpose_f16<f16><<<dim3(D / 32, KL / 32, B), tb, 0, stream>>>(
        kx_h, kxT, KL, D, (long long)KL * D, (long long)D * KL);
    // S = qw @ kx^T  (raw logits straight into d_out score region, fp32)
    gemm_bt256<false, false><<<dim3(8, 8, 8), b512, 0, stream>>>(
        qw_h, kx_h, nullptr, score, QL, KL, D, D / 64,
        (long long)QL * D, (long long)KL * D, (long long)QL * KL);
    // softmax in place + fp16 P for PV
    softmax_rows<<<B * QL, b256, 0, stream>>>(score, P_h);
    // out_attn = P @ kx   (via kxT, bt-form)
    gemm_bt256<true, false><<<dim3(4, 8, 8), b512, 0, stream>>>(
        P_h, kxT, nullptr, oa_h, QL, D, KL, KL / 64,
        (long long)QL * KL, (long long)D * KL, (long long)QL * D);
    // out = out_attn @ Wp^T + bp
    gemm_bt256<false, true><<<dim3(4, 64, 1), b512, 0, stream>>>(
        oa_h, Wp_h, bp, out, (int)BT, D, D, D / 64, 0, 0, 0);
}